// Round 6
// baseline (450.368 us; speedup 1.0000x reference)
//
#include <hip/hip_runtime.h>

// ---------------------------------------------------------------------------
// Problem constants (from reference)
// ---------------------------------------------------------------------------
constexpr int H = 2, C = 32, HC = 64;
constexpr int NB = 128, TPER = 1024;
constexpr int NTASKS = NB * TPER;      // 131072
constexpr int NDATA = 65536;
constexpr int EE = 1048576;
constexpr int NDEV = 4;
constexpr int TASK_D = 12, DATA_D = 5, DEV_D = 12, EDGE_D = 3;
constexpr int EMB = 2 * C + TASK_D;    // 76
constexpr int HEAD_IN = 2 * EMB + NDEV * DEV_D; // 200
constexpr int ND2 = 2 * NTASKS;        // unified CSR destination space (both convs)

constexpr int PSLICES = 256;                      // slices over unified 2*EE
constexpr int PSLICE_LEN = 2 * EE / PSLICES;      // 8192 edges per slice

typedef float f4raw __attribute__((ext_vector_type(4)));

// DPP 16-lane sum: xor1 (quad_perm [1,0,3,2]=0xB1), xor2 ([2,3,0,1]=0x4E),
// then row_half_mirror (0x141, ==xor4 once quads are uniform) and row_mirror
// (0x140, ==xor8 once 8-groups are uniform). All VALU-pipe, no LDS.
template <int CTRL>
__device__ __forceinline__ float dpp_addstep(float v) {
    int t = __builtin_amdgcn_update_dpp(0, __float_as_int(v), CTRL, 0xF, 0xF, true);
    return v + __int_as_float(t);
}
__device__ __forceinline__ float sum16(float v) {
    v = dpp_addstep<0xB1>(v);
    v = dpp_addstep<0x4E>(v);
    v = dpp_addstep<0x141>(v);
    v = dpp_addstep<0x140>(v);
    return v;
}

// ---------------------------------------------------------------------------
// proj: out[N,64] = x[N,K] @ W[K,64] + b   (one wave per RPW rows)
// ---------------------------------------------------------------------------
template <int K, int RPW>
__global__ void proj_kernel(const float* __restrict__ x, const float* __restrict__ W,
                            const float* __restrict__ bvec, float* __restrict__ out, int N) {
    int wave = (blockIdx.x * blockDim.x + threadIdx.x) >> 6;
    int lane = threadIdx.x & 63;
    float w[K];
#pragma unroll
    for (int k = 0; k < K; ++k) w[k] = W[k * 64 + lane];
    float bv = bvec[lane];
#pragma unroll
    for (int r = 0; r < RPW; ++r) {
        int row = wave * RPW + r;
        if (row >= N) return;
        float a = bv;
#pragma unroll
        for (int k = 0; k < K; ++k) a = fmaf(x[(size_t)row * K + k], w[k], a);
        out[(size_t)row * 64 + lane] = a;
    }
}

// dual proj for conv2: both Wl and Wr projections of tasks_x in one pass
template <int RPW>
__global__ void proj_dual_kernel(const float* __restrict__ x,
                                 const float* __restrict__ Wa, const float* __restrict__ ba,
                                 const float* __restrict__ Wb, const float* __restrict__ bb,
                                 float* __restrict__ outA, float* __restrict__ outB, int N) {
    int wave = (blockIdx.x * blockDim.x + threadIdx.x) >> 6;
    int lane = threadIdx.x & 63;
    float wa[12], wb[12];
#pragma unroll
    for (int k = 0; k < 12; ++k) { wa[k] = Wa[k * 64 + lane]; wb[k] = Wb[k * 64 + lane]; }
    float bav = ba[lane], bbv = bb[lane];
#pragma unroll
    for (int r = 0; r < RPW; ++r) {
        int row = wave * RPW + r;
        if (row >= N) return;
        const float4* xp = (const float4*)(x + (size_t)row * 12);
        float4 x0 = xp[0], x1 = xp[1], x2 = xp[2];
        float xf[12] = { x0.x, x0.y, x0.z, x0.w, x1.x, x1.y, x1.z, x1.w,
                         x2.x, x2.y, x2.z, x2.w };
        float a = bav, b = bbv;
#pragma unroll
        for (int k = 0; k < 12; ++k) { a = fmaf(xf[k], wa[k], a); b = fmaf(xf[k], wb[k], b); }
        outA[(size_t)row * 64 + lane] = a;
        outB[(size_t)row * 64 + lane] = b;
    }
}

// ---------------------------------------------------------------------------
// XCD-local degree count: block (slice, rr) counts only dsts in range rr.
// Streaming reads are non-temporal so they don't evict the L2-resident
// deg/cursor/csr write regions.
// ---------------------------------------------------------------------------
__global__ __launch_bounds__(256) void count_part_kernel(
        const int* __restrict__ ei_dt, const int* __restrict__ ei_tt,
        int* __restrict__ deg) {
    int rr = blockIdx.x & 7;
    int slice = blockIdx.x >> 3;
    int base = slice * PSLICE_LEN;
    bool isc1 = base < EE;                         // PSLICE_LEN divides EE
    int dlo = (rr << 14) + (isc1 ? 0 : NTASKS);
    int dhi = dlo + (1 << 14);
    const int* dstp = isc1 ? (ei_dt + EE + base) : (ei_tt + EE + (base - EE));
    int doff = isc1 ? 0 : NTASKS;
    for (int i = threadIdx.x; i < PSLICE_LEN; i += 256) {
        int d = __builtin_nontemporal_load(dstp + i) + doff;
        if (d >= dlo && d < dhi) atomicAdd(&deg[d], 1);
    }
}

__global__ void scan1_kernel(const int* __restrict__ deg, int* __restrict__ excl,
                             int* __restrict__ bsum) {
    __shared__ int sm[256];
    int i = blockIdx.x * 256 + threadIdx.x;
    int v = deg[i];
    sm[threadIdx.x] = v; __syncthreads();
    for (int d = 1; d < 256; d <<= 1) {
        int t = (threadIdx.x >= d) ? sm[threadIdx.x - d] : 0;
        __syncthreads();
        sm[threadIdx.x] += t;
        __syncthreads();
    }
    excl[i] = sm[threadIdx.x] - v;
    if (threadIdx.x == 255) bsum[blockIdx.x] = sm[255];
}

__global__ void scan2_kernel(int* __restrict__ bsum) {  // 1 block, 1024 threads
    __shared__ int sm[1024];
    int v = bsum[threadIdx.x];
    sm[threadIdx.x] = v; __syncthreads();
    for (int d = 1; d < 1024; d <<= 1) {
        int t = (threadIdx.x >= d) ? sm[threadIdx.x - d] : 0;
        __syncthreads();
        sm[threadIdx.x] += t;
        __syncthreads();
    }
    bsum[threadIdx.x] = sm[threadIdx.x] - v;  // exclusive
}

__global__ void scan3_kernel(int* __restrict__ excl, const int* __restrict__ bsum,
                             int* __restrict__ cursor) {
    int i = blockIdx.x * 256 + threadIdx.x;
    int o = excl[i] + bsum[blockIdx.x];
    excl[i] = o;       // offsets
    cursor[i] = o;     // running cursor for scatter; becomes "ends" afterwards
}

// ---------------------------------------------------------------------------
// XCD-local partitioned scatter with non-temporal streaming reads: the CSR
// write region per range (~2MB) stays L2-resident so partial-line 16B/4B
// writes merge to full lines before writeback.
// ---------------------------------------------------------------------------
__global__ __launch_bounds__(256) void scatter_part_kernel(
        const int* __restrict__ ei_dt, const float* __restrict__ ea,
        const int* __restrict__ ei_tt, int* __restrict__ cursor,
        float4* __restrict__ csr1, int* __restrict__ csr2) {
    int rr = blockIdx.x & 7;
    int slice = blockIdx.x >> 3;
    int base = slice * PSLICE_LEN;
    bool isc1 = base < EE;
    int dlo = (rr << 14) + (isc1 ? 0 : NTASKS);
    int dhi = dlo + (1 << 14);
    if (isc1) {
        for (int i = threadIdx.x; i < PSLICE_LEN; i += 256) {
            int e = base + i;
            int d = __builtin_nontemporal_load(ei_dt + EE + e);
            if (d >= dlo && d < dhi) {
                int s = __builtin_nontemporal_load(ei_dt + e);
                float a0 = __builtin_nontemporal_load(ea + (size_t)e * 3 + 0);
                float a1 = __builtin_nontemporal_load(ea + (size_t)e * 3 + 1);
                float a2 = __builtin_nontemporal_load(ea + (size_t)e * 3 + 2);
                int pos = atomicAdd(&cursor[d], 1);      // pos < EE
                csr1[pos] = make_float4(__int_as_float(s), a0, a1, a2);
            }
        }
    } else {
        for (int i = threadIdx.x; i < PSLICE_LEN; i += 256) {
            int ee = base - EE + i;
            int d = NTASKS + __builtin_nontemporal_load(ei_tt + EE + ee);
            if (d >= dlo && d < dhi) {
                int s = __builtin_nontemporal_load(ei_tt + ee);
                int pos = atomicAdd(&cursor[d], 1);      // pos in [EE, 2EE)
                csr2[pos - EE] = s;
            }
        }
    }
}

// ---------------------------------------------------------------------------
// Fused GATv2 aggregation, 2 edges per wave (one per 32-lane half).
// Lane = half*32 + c2; the lane holds channel pair (2*c2, 2*c2+1) as float2.
// Score reduce: DPP sum within 16-lane groups (head-major layout, H*C=64).
// CSR/xr streams are non-temporal so the gather table keeps the L2.
// ---------------------------------------------------------------------------
template <bool HAS_EA>
__global__ __launch_bounds__(256) void gat_gather_kernel(
        const float4* __restrict__ csr1,    // conv1 packed entries (HAS_EA)
        const int* __restrict__ csr2adj,    // conv2 src array, pre-offset by -EE
        const int* __restrict__ offsets, const int* __restrict__ ends,
        const float* __restrict__ xlt,      // [Nsrc, 64] projected source table
        const float* __restrict__ xrt,      // [NTASKS, 64] projected dest table
        const float* __restrict__ We, const float* __restrict__ att,
        const float* __restrict__ tx,       // tasks_x for residual
        const float* __restrict__ Wres, const float* __restrict__ bias,
        const float* __restrict__ g, const float* __restrict__ bln,
        float* __restrict__ out) {
    int wave = (blockIdx.x * blockDim.x + threadIdx.x) >> 6;
    int lane = threadIdx.x & 63;
    int half = lane >> 5;              // which edge slot this lane serves
    int c2 = lane & 31;                // channel-pair index
    int t = wave;                      // destination task id

    float2 att2 = ((const float2*)att)[c2];
    float2 we0, we1, we2;
    if (HAS_EA) {
        we0 = ((const float2*)We)[c2];
        we1 = ((const float2*)(We + 64))[c2];
        we2 = ((const float2*)(We + 128))[c2];
    }
    float xr2x = __builtin_nontemporal_load(xrt + (size_t)t * 64 + 2 * c2);
    float xr2y = __builtin_nontemporal_load(xrt + (size_t)t * 64 + 2 * c2 + 1);

    int beg = offsets[t], end = ends[t];
    float den = 0.f;
    float2 accv = make_float2(0.f, 0.f);

    for (int i0 = beg; i0 < end; i0 += 8) {
        // 4 edges per half per iteration: e = i0 + 2*j + half
        int srcs[4];
        float ea0[4], ea1[4], ea2[4];
#pragma unroll
        for (int j = 0; j < 4; ++j) {
            int e = i0 + 2 * j + half;
            e = (e < end) ? e : beg;                 // clamp to a valid edge
            if (HAS_EA) {
                f4raw epk = __builtin_nontemporal_load((const f4raw*)(csr1 + e));
                srcs[j] = __float_as_int(epk.x);
                ea0[j] = epk.y; ea1[j] = epk.z; ea2[j] = epk.w;
            } else {
                srcs[j] = __builtin_nontemporal_load(csr2adj + e);
            }
        }
        float2 gv[4];
#pragma unroll
        for (int j = 0; j < 4; ++j)                  // 4 gathers in flight (8B each)
            gv[j] = *(const float2*)(xlt + (size_t)srcs[j] * 64 + 2 * c2);
        float p[4];
#pragma unroll
        for (int j = 0; j < 4; ++j) {
            float mx = gv[j].x + xr2x;
            float my = gv[j].y + xr2y;
            if (HAS_EA) {
                mx = fmaf(ea0[j], we0.x, fmaf(ea1[j], we1.x, fmaf(ea2[j], we2.x, mx)));
                my = fmaf(ea0[j], we0.y, fmaf(ea1[j], we1.y, fmaf(ea2[j], we2.y, my)));
            }
            float lx = fmaxf(mx, 0.f) + 0.2f * fminf(mx, 0.f);
            float ly = fmaxf(my, 0.f) + 0.2f * fminf(my, 0.f);
            p[j] = fmaf(att2.y, ly, att2.x * lx);
        }
        // 16-lane sums on the VALU pipe (no LDS), one per edge slot
#pragma unroll
        for (int j = 0; j < 4; ++j) p[j] = sum16(p[j]);
#pragma unroll
        for (int j = 0; j < 4; ++j) {
            float ex = __expf(p[j]);
            ex = (i0 + 2 * j + half < end) ? ex : 0.f;   // mask tail
            den += ex;
            accv.x = fmaf(ex, gv[j].x, accv.x);
            accv.y = fmaf(ex, gv[j].y, accv.y);
        }
    }

    // combine the two edge-halves (lane l pairs with l^32: same head, same pair)
    den += __shfl_xor(den, 32, 64);
    accv.x += __shfl_xor(accv.x, 32, 64);
    accv.y += __shfl_xor(accv.y, 32, 64);
    float inv = 1.0f / (den + 1e-16f);
    float ox = accv.x * inv, oy = accv.y * inv;
    // head mean: channel 2*c2 (this head) pairs with channel 2*(c2^16) (other head)
    float hx = 0.5f * (ox + __shfl_xor(ox, 16, 64));
    float hy = 0.5f * (oy + __shfl_xor(oy, 16, 64));
    // redistribute to lane=c layout: lane c reads pair c>>1 comp c&1 (from lanes 0-15)
    int c = lane & 31;
    int srcl = c >> 1;
    float ra = __shfl(hx, srcl, 64);
    float rb = __shfl(hy, srcl, 64);
    float hm = (c & 1) ? rb : ra;

    // residual + LayerNorm + leaky(0.01)
    const float4* tp = (const float4*)(tx + (size_t)t * 12);
    float4 t0 = tp[0], t1 = tp[1], t2 = tp[2];
    float tf[12] = { t0.x, t0.y, t0.z, t0.w, t1.x, t1.y, t1.z, t1.w,
                     t2.x, t2.y, t2.z, t2.w };
    float v2 = hm + bias[c];
#pragma unroll
    for (int k = 0; k < 12; ++k) v2 = fmaf(tf[k], Wres[k * 32 + c], v2);
    float ssum = sum16(v2);
    ssum += __shfl_xor(ssum, 16, 64);
    float mean = ssum * (1.0f / 32.0f);
    float dd = v2 - mean;
    float q = sum16(dd * dd);
    q += __shfl_xor(q, 16, 64);
    float var = q * (1.0f / 32.0f);
    float y = dd * rsqrtf(var + 1e-5f) * g[c] + bln[c];
    y = (y >= 0.f ? y : 0.01f * y);
    if (lane < 32) out[(size_t)t * 32 + c] = y;
}

// ---------------------------------------------------------------------------
// pool: glob[g][j] += sum over 64-task chunk of emb[task][j]
// ---------------------------------------------------------------------------
__global__ void pool_kernel(const float* __restrict__ tx, const float* __restrict__ dft,
                            const float* __restrict__ tft, float* __restrict__ glob) {
    int g = blockIdx.x >> 4;
    int ch = blockIdx.x & 15;
    int j = threadIdx.x;
    if (j >= EMB) return;
    int base = g * TPER + ch * 64;
    float s = 0.0f;
    for (int t = 0; t < 64; ++t) {
        int task = base + t;
        float v;
        if (j < 12)      v = tx[(size_t)task * 12 + j];
        else if (j < 44) v = dft[(size_t)task * 32 + (j - 12)];
        else             v = tft[(size_t)task * 32 + (j - 44)];
        s += v;
    }
    atomicAdd(&glob[g * EMB + j], s);
}

// ---------------------------------------------------------------------------
// head: per-graph cand/glob/dev concat -> [200] @ h1_W -> LN -> leaky -> h2
// ---------------------------------------------------------------------------
__global__ void head_kernel(const float* __restrict__ tx, const float* __restrict__ dft,
                            const float* __restrict__ tft, const float* __restrict__ glob,
                            const float* __restrict__ devx, const float* __restrict__ counts,
                            const int* __restrict__ ptrv,
                            const float* __restrict__ h1_W, const float* __restrict__ h1_b,
                            const float* __restrict__ hln_g, const float* __restrict__ hln_b,
                            const float* __restrict__ h2_W, const float* __restrict__ h2_b,
                            float* __restrict__ out) {
    __shared__ float xs[HEAD_IN];
    __shared__ float ys[32];
    int b = blockIdx.x;
    int l = threadIdx.x; // 64 threads
    int p = ptrv[b];
    float inv = 1.0f / fmaxf(counts[b], 1.0f);
    for (int j = l; j < HEAD_IN; j += 64) {
        float v;
        if (j < 12)       v = tx[(size_t)p * 12 + j];
        else if (j < 44)  v = dft[(size_t)p * 32 + (j - 12)];
        else if (j < 76)  v = tft[(size_t)p * 32 + (j - 44)];
        else if (j < 152) v = glob[b * EMB + (j - 76)] * inv;
        else              v = devx[b * (NDEV * DEV_D) + (j - 152)];
        xs[j] = v;
    }
    __syncthreads();
    if (l < 32) {
        float h = h1_b[l];
        for (int k = 0; k < HEAD_IN; ++k)
            h += xs[k] * h1_W[k * 32 + l];
        float s = h;
#pragma unroll
        for (int off = 16; off; off >>= 1) s += __shfl_xor(s, off, 64);
        float mean = s * (1.0f / 32.0f);
        float dd = h - mean;
        float q = dd * dd;
#pragma unroll
        for (int off = 16; off; off >>= 1) q += __shfl_xor(q, off, 64);
        float var = q * (1.0f / 32.0f);
        float y = dd * rsqrtf(var + 1e-5f) * hln_g[l] + hln_b[l];
        ys[l] = (y >= 0.0f ? y : 0.01f * y);
    }
    __syncthreads();
    if (l < NDEV - 1) {
        float o = h2_b[l];
        for (int c = 0; c < 32; ++c)
            o += ys[c] * h2_W[c * 3 + l];
        out[b * (NDEV - 1) + l] = o;
    }
}

// ---------------------------------------------------------------------------
// launch
// ---------------------------------------------------------------------------
extern "C" void kernel_launch(void* const* d_in, const int* in_sizes, int n_in,
                              void* d_out, int out_size, void* d_ws, size_t ws_size,
                              hipStream_t stream) {
    const float* tasks_x   = (const float*)d_in[0];
    const float* data_x    = (const float*)d_in[1];
    const float* devices_x = (const float*)d_in[2];
    const int*   ei_dt     = (const int*)d_in[3];
    const float* ea_dt     = (const float*)d_in[4];
    const int*   ei_tt     = (const int*)d_in[5];
    // d_in[6] = batch (unused: graphs are contiguous TPER chunks)
    const int*   ptrv      = (const int*)d_in[7];
    const float* counts    = (const float*)d_in[8];
    const float* c1_Wl   = (const float*)d_in[9];
    const float* c1_bl   = (const float*)d_in[10];
    const float* c1_Wr   = (const float*)d_in[11];
    const float* c1_br   = (const float*)d_in[12];
    const float* c1_We   = (const float*)d_in[13];
    const float* c1_att  = (const float*)d_in[14];
    const float* c1_Wres = (const float*)d_in[15];
    const float* c1_bias = (const float*)d_in[16];
    const float* c2_Wl   = (const float*)d_in[17];
    const float* c2_bl   = (const float*)d_in[18];
    const float* c2_Wr   = (const float*)d_in[19];
    const float* c2_br   = (const float*)d_in[20];
    const float* c2_att  = (const float*)d_in[21];
    const float* c2_Wres = (const float*)d_in[22];
    const float* c2_bias = (const float*)d_in[23];
    const float* ln1_g = (const float*)d_in[24];
    const float* ln1_b = (const float*)d_in[25];
    const float* ln2_g = (const float*)d_in[26];
    const float* ln2_b = (const float*)d_in[27];
    const float* h1_W  = (const float*)d_in[28];
    const float* h1_b  = (const float*)d_in[29];
    const float* hln_g = (const float*)d_in[30];
    const float* hln_b = (const float*)d_in[31];
    const float* h2_W  = (const float*)d_in[32];
    const float* h2_b  = (const float*)d_in[33];
    float* out = (float*)d_out;

    // workspace layout (~119MB)
    char* ws = (char*)d_ws;
    size_t off = 0;
    auto alloc = [&](size_t bytes) -> void* {
        void* p = (void*)(ws + off);
        off += (bytes + 255) & ~(size_t)255;
        return p;
    };
    int*    deg     = (int*)alloc((size_t)ND2 * 4);
    int*    offsets = (int*)alloc((size_t)ND2 * 4);
    int*    cursor  = (int*)alloc((size_t)ND2 * 4);
    int*    bsum    = (int*)alloc(1024 * 4);
    float4* csr1    = (float4*)alloc((size_t)EE * 16);        // conv1 packed
    int*    csr2    = (int*)alloc((size_t)EE * 4);            // conv2 src
    float*  tabA    = (float*)alloc((size_t)NTASKS * 64 * 4); // xl table (reused)
    float*  tabB    = (float*)alloc((size_t)NTASKS * 64 * 4); // xr table (reused)
    float*  dft     = (float*)alloc((size_t)NTASKS * 32 * 4);
    float*  tft     = (float*)alloc((size_t)NTASKS * 32 * 4);
    float*  glob    = (float*)alloc((size_t)NB * EMB * 4);
    if (off > ws_size) return;

    const int BLK = 256;

    // ---- unified CSR build over both edge relations (XCD-local partitioned) ----
    hipMemsetAsync(deg, 0, (size_t)ND2 * 4, stream);
    count_part_kernel<<<PSLICES * 8, BLK, 0, stream>>>(ei_dt, ei_tt, deg);
    scan1_kernel<<<ND2 / 256, 256, 0, stream>>>(deg, offsets, bsum);
    scan2_kernel<<<1, 1024, 0, stream>>>(bsum);
    scan3_kernel<<<ND2 / 256, 256, 0, stream>>>(offsets, bsum, cursor);
    scatter_part_kernel<<<PSLICES * 8, BLK, 0, stream>>>(ei_dt, ea_dt, ei_tt, cursor,
                                                         csr1, csr2);

    // ---- conv1: data -> tasks ----
    proj_kernel<DATA_D, 4><<<(NDATA / 4 + 3) / 4, BLK, 0, stream>>>(data_x, c1_Wl, c1_bl, tabA, NDATA);
    proj_kernel<TASK_D, 4><<<(NTASKS / 4 + 3) / 4, BLK, 0, stream>>>(tasks_x, c1_Wr, c1_br, tabB, NTASKS);
    gat_gather_kernel<true><<<NTASKS / 4, BLK, 0, stream>>>(
        csr1, nullptr, offsets, cursor, tabA, tabB, c1_We, c1_att,
        tasks_x, c1_Wres, c1_bias, ln1_g, ln1_b, dft);

    // ---- conv2: tasks -> tasks (tables reused after gat1 completes) ----
    proj_dual_kernel<4><<<(NTASKS / 4 + 3) / 4, BLK, 0, stream>>>(
        tasks_x, c2_Wl, c2_bl, c2_Wr, c2_br, tabA, tabB, NTASKS);
    gat_gather_kernel<false><<<NTASKS / 4, BLK, 0, stream>>>(
        nullptr, csr2 - EE, offsets + NTASKS, cursor + NTASKS, tabA, tabB, nullptr, c2_att,
        tasks_x, c2_Wres, c2_bias, ln2_g, ln2_b, tft);

    // ---- pooling + head ----
    hipMemsetAsync(glob, 0, (size_t)NB * EMB * 4, stream);
    pool_kernel<<<NB * 16, 128, 0, stream>>>(tasks_x, dft, tft, glob);
    head_kernel<<<NB, 64, 0, stream>>>(tasks_x, dft, tft, glob, devices_x, counts, ptrv,
                                       h1_W, h1_b, hln_g, hln_b, h2_W, h2_b, out);
}

// Round 7
// 403.486 us; speedup vs baseline: 1.1162x; 1.1162x over previous
//
#include <hip/hip_runtime.h>

// ---------------------------------------------------------------------------
// Problem constants (from reference)
// ---------------------------------------------------------------------------
constexpr int H = 2, C = 32, HC = 64;
constexpr int NB = 128, TPER = 1024;
constexpr int NTASKS = NB * TPER;      // 131072
constexpr int NDATA = 65536;
constexpr int EE = 1048576;
constexpr int NDEV = 4;
constexpr int TASK_D = 12, DATA_D = 5, DEV_D = 12, EDGE_D = 3;
constexpr int EMB = 2 * C + TASK_D;    // 76
constexpr int HEAD_IN = 2 * EMB + NDEV * DEV_D; // 200
constexpr int ND2 = 2 * NTASKS;        // unified CSR destination space (both convs)

constexpr int PSLICES = 256;                      // slices over unified 2*EE
constexpr int PSLICE_LEN = 2 * EE / PSLICES;      // 8192 edges per slice

typedef float f4raw __attribute__((ext_vector_type(4)));

// DPP 16-lane sum: xor1 (quad_perm), xor2, row_half_mirror, row_mirror.
// All VALU-pipe, no LDS traffic, stays within 16-lane groups.
template <int CTRL>
__device__ __forceinline__ float dpp_addstep(float v) {
    int t = __builtin_amdgcn_update_dpp(0, __float_as_int(v), CTRL, 0xF, 0xF, true);
    return v + __int_as_float(t);
}
__device__ __forceinline__ float sum16(float v) {
    v = dpp_addstep<0xB1>(v);
    v = dpp_addstep<0x4E>(v);
    v = dpp_addstep<0x141>(v);
    v = dpp_addstep<0x140>(v);
    return v;
}

// ---------------------------------------------------------------------------
// proj: out[N,64] = x[N,K] @ W[K,64] + b   (one wave per RPW rows)
// ---------------------------------------------------------------------------
template <int K, int RPW>
__global__ void proj_kernel(const float* __restrict__ x, const float* __restrict__ W,
                            const float* __restrict__ bvec, float* __restrict__ out, int N) {
    int wave = (blockIdx.x * blockDim.x + threadIdx.x) >> 6;
    int lane = threadIdx.x & 63;
    float w[K];
#pragma unroll
    for (int k = 0; k < K; ++k) w[k] = W[k * 64 + lane];
    float bv = bvec[lane];
#pragma unroll
    for (int r = 0; r < RPW; ++r) {
        int row = wave * RPW + r;
        if (row >= N) return;
        float a = bv;
#pragma unroll
        for (int k = 0; k < K; ++k) a = fmaf(x[(size_t)row * K + k], w[k], a);
        out[(size_t)row * 64 + lane] = a;
    }
}

// dual proj for conv2: both Wl and Wr projections of tasks_x in one pass
template <int RPW>
__global__ void proj_dual_kernel(const float* __restrict__ x,
                                 const float* __restrict__ Wa, const float* __restrict__ ba,
                                 const float* __restrict__ Wb, const float* __restrict__ bb,
                                 float* __restrict__ outA, float* __restrict__ outB, int N) {
    int wave = (blockIdx.x * blockDim.x + threadIdx.x) >> 6;
    int lane = threadIdx.x & 63;
    float wa[12], wb[12];
#pragma unroll
    for (int k = 0; k < 12; ++k) { wa[k] = Wa[k * 64 + lane]; wb[k] = Wb[k * 64 + lane]; }
    float bav = ba[lane], bbv = bb[lane];
#pragma unroll
    for (int r = 0; r < RPW; ++r) {
        int row = wave * RPW + r;
        if (row >= N) return;
        const float4* xp = (const float4*)(x + (size_t)row * 12);
        float4 x0 = xp[0], x1 = xp[1], x2 = xp[2];
        float xf[12] = { x0.x, x0.y, x0.z, x0.w, x1.x, x1.y, x1.z, x1.w,
                         x2.x, x2.y, x2.z, x2.w };
        float a = bav, b = bbv;
#pragma unroll
        for (int k = 0; k < 12; ++k) { a = fmaf(xf[k], wa[k], a); b = fmaf(xf[k], wb[k], b); }
        outA[(size_t)row * 64 + lane] = a;
        outB[(size_t)row * 64 + lane] = b;
    }
}

// ---------------------------------------------------------------------------
// XCD-local degree count: block (slice, rr) counts only dsts in range rr.
// ---------------------------------------------------------------------------
__global__ __launch_bounds__(256) void count_part_kernel(
        const int* __restrict__ ei_dt, const int* __restrict__ ei_tt,
        int* __restrict__ deg) {
    int rr = blockIdx.x & 7;
    int slice = blockIdx.x >> 3;
    int base = slice * PSLICE_LEN;
    bool isc1 = base < EE;                         // PSLICE_LEN divides EE
    int dlo = (rr << 14) + (isc1 ? 0 : NTASKS);
    int dhi = dlo + (1 << 14);
    const int* dstp = isc1 ? (ei_dt + EE + base) : (ei_tt + EE + (base - EE));
    int doff = isc1 ? 0 : NTASKS;
    for (int i = threadIdx.x; i < PSLICE_LEN; i += 256) {
        int d = dstp[i] + doff;
        if (d >= dlo && d < dhi) atomicAdd(&deg[d], 1);
    }
}

__global__ void scan1_kernel(const int* __restrict__ deg, int* __restrict__ excl,
                             int* __restrict__ bsum) {
    __shared__ int sm[256];
    int i = blockIdx.x * 256 + threadIdx.x;
    int v = deg[i];
    sm[threadIdx.x] = v; __syncthreads();
    for (int d = 1; d < 256; d <<= 1) {
        int t = (threadIdx.x >= d) ? sm[threadIdx.x - d] : 0;
        __syncthreads();
        sm[threadIdx.x] += t;
        __syncthreads();
    }
    excl[i] = sm[threadIdx.x] - v;
    if (threadIdx.x == 255) bsum[blockIdx.x] = sm[255];
}

__global__ void scan2_kernel(int* __restrict__ bsum) {  // 1 block, 1024 threads
    __shared__ int sm[1024];
    int v = bsum[threadIdx.x];
    sm[threadIdx.x] = v; __syncthreads();
    for (int d = 1; d < 1024; d <<= 1) {
        int t = (threadIdx.x >= d) ? sm[threadIdx.x - d] : 0;
        __syncthreads();
        sm[threadIdx.x] += t;
        __syncthreads();
    }
    bsum[threadIdx.x] = sm[threadIdx.x] - v;  // exclusive
}

__global__ void scan3_kernel(int* __restrict__ excl, const int* __restrict__ bsum,
                             int* __restrict__ cursor) {
    int i = blockIdx.x * 256 + threadIdx.x;
    int o = excl[i] + bsum[blockIdx.x];
    excl[i] = o;       // offsets
    cursor[i] = o;     // running cursor for scatter; becomes "ends" afterwards
}

// ---------------------------------------------------------------------------
// XCD-local partitioned scatter (round-5 form: plain loads).
// ---------------------------------------------------------------------------
__global__ __launch_bounds__(256) void scatter_part_kernel(
        const int* __restrict__ ei_dt, const float* __restrict__ ea,
        const int* __restrict__ ei_tt, int* __restrict__ cursor,
        float4* __restrict__ csr1, int* __restrict__ csr2) {
    int rr = blockIdx.x & 7;
    int slice = blockIdx.x >> 3;
    int base = slice * PSLICE_LEN;
    bool isc1 = base < EE;
    int dlo = (rr << 14) + (isc1 ? 0 : NTASKS);
    int dhi = dlo + (1 << 14);
    if (isc1) {
        for (int i = threadIdx.x; i < PSLICE_LEN; i += 256) {
            int e = base + i;
            int d = ei_dt[EE + e];
            if (d >= dlo && d < dhi) {
                int s = ei_dt[e];
                int pos = atomicAdd(&cursor[d], 1);      // pos < EE
                csr1[pos] = make_float4(__int_as_float(s), ea[(size_t)e * 3 + 0],
                                        ea[(size_t)e * 3 + 1], ea[(size_t)e * 3 + 2]);
            }
        }
    } else {
        for (int i = threadIdx.x; i < PSLICE_LEN; i += 256) {
            int ee = base - EE + i;
            int d = NTASKS + ei_tt[EE + ee];
            if (d >= dlo && d < dhi) {
                int s = ei_tt[ee];
                int pos = atomicAdd(&cursor[d], 1);      // pos in [EE, 2EE)
                csr2[pos - EE] = s;
            }
        }
    }
}

// ---------------------------------------------------------------------------
// Fused GATv2 aggregation, 2 DESTINATIONS per wave (one per 32-lane half).
// Lane = half*32 + c2; half h owns dst t_h; lane holds channel pair
// (2*c2, 2*c2+1). Score reduce: DPP sum within 16-lane groups (head-major
// layout). Block->dst mapping is XCD-aligned with the scatter partition so
// csr reads hit the local L2. All 64 lanes write output (one dst per half).
// ---------------------------------------------------------------------------
template <bool HAS_EA>
__global__ __launch_bounds__(256) void gat_gather_kernel(
        const float4* __restrict__ csr1,    // conv1 packed entries (HAS_EA)
        const int* __restrict__ csr2adj,    // conv2 src array, pre-offset by -EE
        const int* __restrict__ offsets, const int* __restrict__ ends,
        const float* __restrict__ xlt,      // [Nsrc, 64] projected source table
        const float* __restrict__ xrt,      // [NTASKS, 64] projected dest table
        const float* __restrict__ We, const float* __restrict__ att,
        const float* __restrict__ tx,       // tasks_x for residual
        const float* __restrict__ Wres, const float* __restrict__ bias,
        const float* __restrict__ g, const float* __restrict__ bln,
        float* __restrict__ out) {
    int widx = threadIdx.x >> 6;       // wave in block: 0..3
    int lane = threadIdx.x & 63;
    int half = lane >> 5;              // which dst this half serves
    int c2 = lane & 31;                // channel-pair index
    int rr = blockIdx.x & 7;           // dst range (XCD-aligned with scatter)
    int q = blockIdx.x >> 3;
    int t = (rr << 14) + q * 8 + widx * 2 + half;   // this half's dst

    float2 att2 = ((const float2*)att)[c2];
    float2 we0, we1, we2;
    if (HAS_EA) {
        we0 = ((const float2*)We)[c2];
        we1 = ((const float2*)(We + 64))[c2];
        we2 = ((const float2*)(We + 128))[c2];
    }
    float2 xr2 = *(const float2*)(xrt + (size_t)t * 64 + 2 * c2);

    int beg = offsets[t], end = ends[t];
    int len = end - beg;
    int maxlen = max(len, __shfl_xor(len, 32, 64));
    float den = 0.f;
    float2 accv = make_float2(0.f, 0.f);

    for (int i0 = 0; i0 < maxlen; i0 += 4) {
        int srcs[4];
        float ea0[4], ea1[4], ea2[4];
#pragma unroll
        for (int j = 0; j < 4; ++j) {
            int idx = beg + i0 + j;
            idx = (i0 + j < len) ? idx : beg;        // clamp to a valid edge
            if (HAS_EA) {
                f4raw epk = __builtin_nontemporal_load((const f4raw*)(csr1 + idx));
                srcs[j] = __float_as_int(epk.x);
                ea0[j] = epk.y; ea1[j] = epk.z; ea2[j] = epk.w;
            } else {
                srcs[j] = __builtin_nontemporal_load(csr2adj + idx);
            }
        }
        float2 gv[4];
#pragma unroll
        for (int j = 0; j < 4; ++j)                  // 4 gathers in flight (8B each)
            gv[j] = *(const float2*)(xlt + (size_t)srcs[j] * 64 + 2 * c2);
        float p[4];
#pragma unroll
        for (int j = 0; j < 4; ++j) {
            float mx = gv[j].x + xr2.x;
            float my = gv[j].y + xr2.y;
            if (HAS_EA) {
                mx = fmaf(ea0[j], we0.x, fmaf(ea1[j], we1.x, fmaf(ea2[j], we2.x, mx)));
                my = fmaf(ea0[j], we0.y, fmaf(ea1[j], we1.y, fmaf(ea2[j], we2.y, my)));
            }
            float lx = fmaxf(mx, 0.f) + 0.2f * fminf(mx, 0.f);
            float ly = fmaxf(my, 0.f) + 0.2f * fminf(my, 0.f);
            p[j] = fmaf(att2.y, ly, att2.x * lx);
        }
        // 16-lane sums on the VALU pipe (no LDS): per-head logits per edge
#pragma unroll
        for (int j = 0; j < 4; ++j) p[j] = sum16(p[j]);
#pragma unroll
        for (int j = 0; j < 4; ++j) {
            float ex = __expf(p[j]);
            ex = (i0 + j < len) ? ex : 0.f;          // mask tail
            den += ex;
            accv.x = fmaf(ex, gv[j].x, accv.x);
            accv.y = fmaf(ex, gv[j].y, accv.y);
        }
    }

    // finalize per half (each half owns its own dst; no cross-half combine)
    float inv = 1.0f / (den + 1e-16f);
    float ox = accv.x * inv, oy = accv.y * inv;
    // head mean: lane c2 (head c2>=16) pairs with lane c2^16 (other head)
    float hx = 0.5f * (ox + __shfl_xor(ox, 16, 64));
    float hy = 0.5f * (oy + __shfl_xor(oy, 16, 64));
    // redistribute within half: lane c2 wants channel c2 = pair c2>>1, comp c2&1
    int srcl = (half << 5) + (c2 >> 1);
    float ra = __shfl(hx, srcl, 64);
    float rb = __shfl(hy, srcl, 64);
    float hm = (c2 & 1) ? rb : ra;

    // residual + LayerNorm + leaky(0.01), per half
    const float4* tp = (const float4*)(tx + (size_t)t * 12);
    float4 t0 = tp[0], t1 = tp[1], t2 = tp[2];
    float tf[12] = { t0.x, t0.y, t0.z, t0.w, t1.x, t1.y, t1.z, t1.w,
                     t2.x, t2.y, t2.z, t2.w };
    float v2 = hm + bias[c2];
#pragma unroll
    for (int k = 0; k < 12; ++k) v2 = fmaf(tf[k], Wres[k * 32 + c2], v2);
    float ssum = sum16(v2);
    ssum += __shfl_xor(ssum, 16, 64);
    float mean = ssum * (1.0f / 32.0f);
    float dd = v2 - mean;
    float q2 = sum16(dd * dd);
    q2 += __shfl_xor(q2, 16, 64);
    float var = q2 * (1.0f / 32.0f);
    float y = dd * rsqrtf(var + 1e-5f) * g[c2] + bln[c2];
    y = (y >= 0.f ? y : 0.01f * y);
    out[(size_t)t * 32 + c2] = y;      // all 64 lanes write (one dst per half)
}

// ---------------------------------------------------------------------------
// pool: glob[g][j] += sum over 64-task chunk of emb[task][j]
// ---------------------------------------------------------------------------
__global__ void pool_kernel(const float* __restrict__ tx, const float* __restrict__ dft,
                            const float* __restrict__ tft, float* __restrict__ glob) {
    int g = blockIdx.x >> 4;
    int ch = blockIdx.x & 15;
    int j = threadIdx.x;
    if (j >= EMB) return;
    int base = g * TPER + ch * 64;
    float s = 0.0f;
    for (int t = 0; t < 64; ++t) {
        int task = base + t;
        float v;
        if (j < 12)      v = tx[(size_t)task * 12 + j];
        else if (j < 44) v = dft[(size_t)task * 32 + (j - 12)];
        else             v = tft[(size_t)task * 32 + (j - 44)];
        s += v;
    }
    atomicAdd(&glob[g * EMB + j], s);
}

// ---------------------------------------------------------------------------
// head: per-graph cand/glob/dev concat -> [200] @ h1_W -> LN -> leaky -> h2
// ---------------------------------------------------------------------------
__global__ void head_kernel(const float* __restrict__ tx, const float* __restrict__ dft,
                            const float* __restrict__ tft, const float* __restrict__ glob,
                            const float* __restrict__ devx, const float* __restrict__ counts,
                            const int* __restrict__ ptrv,
                            const float* __restrict__ h1_W, const float* __restrict__ h1_b,
                            const float* __restrict__ hln_g, const float* __restrict__ hln_b,
                            const float* __restrict__ h2_W, const float* __restrict__ h2_b,
                            float* __restrict__ out) {
    __shared__ float xs[HEAD_IN];
    __shared__ float ys[32];
    int b = blockIdx.x;
    int l = threadIdx.x; // 64 threads
    int p = ptrv[b];
    float inv = 1.0f / fmaxf(counts[b], 1.0f);
    for (int j = l; j < HEAD_IN; j += 64) {
        float v;
        if (j < 12)       v = tx[(size_t)p * 12 + j];
        else if (j < 44)  v = dft[(size_t)p * 32 + (j - 12)];
        else if (j < 76)  v = tft[(size_t)p * 32 + (j - 44)];
        else if (j < 152) v = glob[b * EMB + (j - 76)] * inv;
        else              v = devx[b * (NDEV * DEV_D) + (j - 152)];
        xs[j] = v;
    }
    __syncthreads();
    if (l < 32) {
        float h = h1_b[l];
        for (int k = 0; k < HEAD_IN; ++k)
            h += xs[k] * h1_W[k * 32 + l];
        float s = h;
#pragma unroll
        for (int off = 16; off; off >>= 1) s += __shfl_xor(s, off, 64);
        float mean = s * (1.0f / 32.0f);
        float dd = h - mean;
        float q = dd * dd;
#pragma unroll
        for (int off = 16; off; off >>= 1) q += __shfl_xor(q, off, 64);
        float var = q * (1.0f / 32.0f);
        float y = dd * rsqrtf(var + 1e-5f) * hln_g[l] + hln_b[l];
        ys[l] = (y >= 0.0f ? y : 0.01f * y);
    }
    __syncthreads();
    if (l < NDEV - 1) {
        float o = h2_b[l];
        for (int c = 0; c < 32; ++c)
            o += ys[c] * h2_W[c * 3 + l];
        out[b * (NDEV - 1) + l] = o;
    }
}

// ---------------------------------------------------------------------------
// launch
// ---------------------------------------------------------------------------
extern "C" void kernel_launch(void* const* d_in, const int* in_sizes, int n_in,
                              void* d_out, int out_size, void* d_ws, size_t ws_size,
                              hipStream_t stream) {
    const float* tasks_x   = (const float*)d_in[0];
    const float* data_x    = (const float*)d_in[1];
    const float* devices_x = (const float*)d_in[2];
    const int*   ei_dt     = (const int*)d_in[3];
    const float* ea_dt     = (const float*)d_in[4];
    const int*   ei_tt     = (const int*)d_in[5];
    // d_in[6] = batch (unused: graphs are contiguous TPER chunks)
    const int*   ptrv      = (const int*)d_in[7];
    const float* counts    = (const float*)d_in[8];
    const float* c1_Wl   = (const float*)d_in[9];
    const float* c1_bl   = (const float*)d_in[10];
    const float* c1_Wr   = (const float*)d_in[11];
    const float* c1_br   = (const float*)d_in[12];
    const float* c1_We   = (const float*)d_in[13];
    const float* c1_att  = (const float*)d_in[14];
    const float* c1_Wres = (const float*)d_in[15];
    const float* c1_bias = (const float*)d_in[16];
    const float* c2_Wl   = (const float*)d_in[17];
    const float* c2_bl   = (const float*)d_in[18];
    const float* c2_Wr   = (const float*)d_in[19];
    const float* c2_br   = (const float*)d_in[20];
    const float* c2_att  = (const float*)d_in[21];
    const float* c2_Wres = (const float*)d_in[22];
    const float* c2_bias = (const float*)d_in[23];
    const float* ln1_g = (const float*)d_in[24];
    const float* ln1_b = (const float*)d_in[25];
    const float* ln2_g = (const float*)d_in[26];
    const float* ln2_b = (const float*)d_in[27];
    const float* h1_W  = (const float*)d_in[28];
    const float* h1_b  = (const float*)d_in[29];
    const float* hln_g = (const float*)d_in[30];
    const float* hln_b = (const float*)d_in[31];
    const float* h2_W  = (const float*)d_in[32];
    const float* h2_b  = (const float*)d_in[33];
    float* out = (float*)d_out;

    // workspace layout (~119MB)
    char* ws = (char*)d_ws;
    size_t off = 0;
    auto alloc = [&](size_t bytes) -> void* {
        void* p = (void*)(ws + off);
        off += (bytes + 255) & ~(size_t)255;
        return p;
    };
    int*    deg     = (int*)alloc((size_t)ND2 * 4);
    int*    offsets = (int*)alloc((size_t)ND2 * 4);
    int*    cursor  = (int*)alloc((size_t)ND2 * 4);
    int*    bsum    = (int*)alloc(1024 * 4);
    float4* csr1    = (float4*)alloc((size_t)EE * 16);        // conv1 packed
    int*    csr2    = (int*)alloc((size_t)EE * 4);            // conv2 src
    float*  tabA    = (float*)alloc((size_t)NTASKS * 64 * 4); // xl table (reused)
    float*  tabB    = (float*)alloc((size_t)NTASKS * 64 * 4); // xr table (reused)
    float*  dft     = (float*)alloc((size_t)NTASKS * 32 * 4);
    float*  tft     = (float*)alloc((size_t)NTASKS * 32 * 4);
    float*  glob    = (float*)alloc((size_t)NB * EMB * 4);
    if (off > ws_size) return;

    const int BLK = 256;

    // ---- unified CSR build over both edge relations (XCD-local partitioned) ----
    hipMemsetAsync(deg, 0, (size_t)ND2 * 4, stream);
    count_part_kernel<<<PSLICES * 8, BLK, 0, stream>>>(ei_dt, ei_tt, deg);
    scan1_kernel<<<ND2 / 256, 256, 0, stream>>>(deg, offsets, bsum);
    scan2_kernel<<<1, 1024, 0, stream>>>(bsum);
    scan3_kernel<<<ND2 / 256, 256, 0, stream>>>(offsets, bsum, cursor);
    scatter_part_kernel<<<PSLICES * 8, BLK, 0, stream>>>(ei_dt, ea_dt, ei_tt, cursor,
                                                         csr1, csr2);

    // ---- conv1: data -> tasks ----
    proj_kernel<DATA_D, 4><<<(NDATA / 4 + 3) / 4, BLK, 0, stream>>>(data_x, c1_Wl, c1_bl, tabA, NDATA);
    proj_kernel<TASK_D, 4><<<(NTASKS / 4 + 3) / 4, BLK, 0, stream>>>(tasks_x, c1_Wr, c1_br, tabB, NTASKS);
    gat_gather_kernel<true><<<NTASKS / 8, BLK, 0, stream>>>(
        csr1, nullptr, offsets, cursor, tabA, tabB, c1_We, c1_att,
        tasks_x, c1_Wres, c1_bias, ln1_g, ln1_b, dft);

    // ---- conv2: tasks -> tasks (tables reused after gat1 completes) ----
    proj_dual_kernel<4><<<(NTASKS / 4 + 3) / 4, BLK, 0, stream>>>(
        tasks_x, c2_Wl, c2_bl, c2_Wr, c2_br, tabA, tabB, NTASKS);
    gat_gather_kernel<false><<<NTASKS / 8, BLK, 0, stream>>>(
        nullptr, csr2 - EE, offsets + NTASKS, cursor + NTASKS, tabA, tabB, nullptr, c2_att,
        tasks_x, c2_Wres, c2_bias, ln2_g, ln2_b, tft);

    // ---- pooling + head ----
    hipMemsetAsync(glob, 0, (size_t)NB * EMB * 4, stream);
    pool_kernel<<<NB * 16, 128, 0, stream>>>(tasks_x, dft, tft, glob);
    head_kernel<<<NB, 64, 0, stream>>>(tasks_x, dft, tft, glob, devices_x, counts, ptrv,
                                       h1_W, h1_b, hln_g, hln_b, h2_W, h2_b, out);
}